// Round 12
// baseline (35.425 us; speedup 1.0000x reference)
//
#include <hip/hip_runtime.h>
#include <stdint.h>

// BLS12-377 Fr: p = 0x12ab655e9a2ca55660b44d1e5c37b00159aa76fed00000010a11800000000001
//
// Reference computes (a*R mod p + b*R mod p) mod p, canonical in [0,p), R = 2^256.
// Inputs a,b each have 4 64-bit limbs < 2^31 (values < 2^223), so a+b < 2^224 < p and
// the result equals (a+b)*R mod p. With s_k = a_k + b_k (< 2^32, no inter-limb carry),
// result = (sum_k s_k * D_k) * 2^-64 mod p where D_k = 2^(320+64k) mod p.
//
// Bounds: T0 = sum s_k*D_k < 2^34*p; REDC1 -> T1 < 5p < 2^255; REDC2 -> T2 < 2p;
// one cond_sub -> canonical, bit-exact vs reference.
//
// Harness dtypes: inputs int32[N*4] (limbs < 2^31), output int32[N*4] = low 32 bits
// of each 64-bit output word = even 32-bit limbs of the canonical residue.
//
// Round 12: hand-built memory pipeline via inline asm (AITER counted-vmcnt
// pattern). Builtin loads are sunk to first use by the compiler (R4/R5/R6/R9
// all failed to pipeline). Inline-asm volatile loads CANNOT move relative to
// each other; counted s_waitcnt vmcnt(N) with the loaded tuples as "+v"
// operands (+ sched_barrier(0), guide rule #18) pins compute after the wait.
// Per thread: issue 4 loads (elements A=idx, B=idx+half) -> vmcnt(2) -> compute
// A (R11 parallel-mad body, ~600cyc, covers B's in-flight latency) -> store A
// -> vmcnt(1) -> compute B -> store B. Exposed HBM latency per 2 elements is
// ~1 wait instead of 2.

namespace {

constexpr uint32_t PL[8] = {
  0x00000001u, 0x0a118000u, 0xd0000001u, 0x59aa76feu,
  0x5c37b001u, 0x60b44d1eu, 0x9a2ca556u, 0x12ab655eu
};

struct U256 { uint32_t l[8]; };

constexpr bool geq_p(const U256& x) {
  for (int i = 7; i >= 0; --i) {
    if (x.l[i] != PL[i]) return x.l[i] > PL[i];
  }
  return true;  // equal
}

// 2^e mod p via double-and-reduce from 2^252 (< p since p > 2^252).
constexpr U256 pow2_mod(int e) {
  U256 x{};
  for (int i = 0; i < 8; ++i) x.l[i] = 0;
  x.l[7] = 0x10000000u;  // 2^252
  for (int it = 0; it < e - 252; ++it) {
    uint32_t carry = 0;
    for (int j = 0; j < 8; ++j) {
      uint32_t nc = x.l[j] >> 31;
      x.l[j] = (x.l[j] << 1) | carry;
      carry = nc;
    }
    if (geq_p(x)) {
      uint64_t borrow = 0;
      for (int j = 0; j < 8; ++j) {
        uint64_t d = (uint64_t)x.l[j] - (uint64_t)PL[j] - borrow;
        x.l[j] = (uint32_t)d;
        borrow = (d >> 32) & 1ull;
      }
    }
  }
  return x;
}

constexpr U256 D0 = pow2_mod(320);
constexpr U256 D1 = pow2_mod(384);
constexpr U256 D2 = pow2_mod(448);
constexpr U256 D3 = pow2_mod(512);

}  // namespace

typedef int v4i __attribute__((ext_vector_type(4)));

// 32-bit add with carry-in/carry-out; maps to v_add_co_u32 / v_addc_co_u32.
__device__ __forceinline__ uint32_t addc32(uint32_t a, uint32_t b, uint32_t cin,
                                           uint32_t* cout) {
#if __has_builtin(__builtin_addc)
  return __builtin_addc(a, b, cin, cout);
#else
  uint64_t s = (uint64_t)a + b + cin;
  *cout = (uint32_t)(s >> 32);
  return (uint32_t)s;
#endif
}

// R11 even/odd-split body: 8 independent mads per row + one addc merge chain.
__device__ __forceinline__ v4i compute_one(const v4i av, const v4i bv) {
  uint32_t s0 = (uint32_t)av.x + (uint32_t)bv.x;
  uint32_t s1 = (uint32_t)av.y + (uint32_t)bv.y;
  uint32_t s2 = (uint32_t)av.z + (uint32_t)bv.z;
  uint32_t s3 = (uint32_t)av.w + (uint32_t)bv.w;

  uint32_t t0, t1, t2, t3, t4, t5, t6, t7, t8;
  uint32_t cc;

  // Row 0: t = s0 * D0
  {
    uint64_t E0 = (uint64_t)s0 * D0.l[0];
    uint64_t O0 = (uint64_t)s0 * D0.l[1];
    uint64_t E1 = (uint64_t)s0 * D0.l[2];
    uint64_t O1 = (uint64_t)s0 * D0.l[3];
    uint64_t E2 = (uint64_t)s0 * D0.l[4];
    uint64_t O2 = (uint64_t)s0 * D0.l[5];
    uint64_t E3 = (uint64_t)s0 * D0.l[6];
    uint64_t O3 = (uint64_t)s0 * D0.l[7];
    t0 = (uint32_t)E0;
    t1 = addc32((uint32_t)(E0 >> 32), (uint32_t)O0, 0u, &cc);
    t2 = addc32((uint32_t)E1, (uint32_t)(O0 >> 32), cc, &cc);
    t3 = addc32((uint32_t)(E1 >> 32), (uint32_t)O1, cc, &cc);
    t4 = addc32((uint32_t)E2, (uint32_t)(O1 >> 32), cc, &cc);
    t5 = addc32((uint32_t)(E2 >> 32), (uint32_t)O2, cc, &cc);
    t6 = addc32((uint32_t)E3, (uint32_t)(O2 >> 32), cc, &cc);
    t7 = addc32((uint32_t)(E3 >> 32), (uint32_t)O3, cc, &cc);
    t8 = (uint32_t)(O3 >> 32) + cc;
  }

  // Rows 1..3: t += s_r * D_r  (E_k = s*D[2k]+t[2k], O_k = s*D[2k+1]+t[2k+1];
  // no overflow: (2^32-1)^2 + 2^32-1 < 2^64)
#define ROW_ACC(s, D)                                                          \
  {                                                                            \
    uint64_t E0 = (uint64_t)(s) * D.l[0] + t0;                                 \
    uint64_t O0 = (uint64_t)(s) * D.l[1] + t1;                                 \
    uint64_t E1 = (uint64_t)(s) * D.l[2] + t2;                                 \
    uint64_t O1 = (uint64_t)(s) * D.l[3] + t3;                                 \
    uint64_t E2 = (uint64_t)(s) * D.l[4] + t4;                                 \
    uint64_t O2 = (uint64_t)(s) * D.l[5] + t5;                                 \
    uint64_t E3 = (uint64_t)(s) * D.l[6] + t6;                                 \
    uint64_t O3 = (uint64_t)(s) * D.l[7] + t7;                                 \
    t0 = (uint32_t)E0;                                                         \
    t1 = addc32((uint32_t)(E0 >> 32), (uint32_t)O0, 0u, &cc);                  \
    t2 = addc32((uint32_t)E1, (uint32_t)(O0 >> 32), cc, &cc);                  \
    t3 = addc32((uint32_t)(E1 >> 32), (uint32_t)O1, cc, &cc);                  \
    t4 = addc32((uint32_t)E2, (uint32_t)(O1 >> 32), cc, &cc);                  \
    t5 = addc32((uint32_t)(E2 >> 32), (uint32_t)O2, cc, &cc);                  \
    t6 = addc32((uint32_t)E3, (uint32_t)(O2 >> 32), cc, &cc);                  \
    t7 = addc32((uint32_t)(E3 >> 32), (uint32_t)O3, cc, &cc);                  \
    t8 = t8 + (uint32_t)(O3 >> 32) + cc;                                       \
  }

  ROW_ACC(s1, D1);
  ROW_ACC(s2, D2);
  ROW_ACC(s3, D3);
#undef ROW_ACC

  // REDC step 1 (9 -> 8 limbs): m = -t0 mod 2^32 (p[0] == 1)
  {
    uint32_t m = 0u - t0;
    uint32_t g = (t0 != 0u) ? 1u : 0u;
    uint64_t O0 = (uint64_t)m * PL[1] + t1;
    uint64_t E1 = (uint64_t)m * PL[2] + t2;
    uint64_t O1 = (uint64_t)m * PL[3] + t3;
    uint64_t E2 = (uint64_t)m * PL[4] + t4;
    uint64_t O2 = (uint64_t)m * PL[5] + t5;
    uint64_t E3 = (uint64_t)m * PL[6] + t6;
    uint64_t O3 = (uint64_t)m * PL[7] + t7;
    t0 = addc32((uint32_t)O0, g, 0u, &cc);
    t1 = addc32((uint32_t)E1, (uint32_t)(O0 >> 32), cc, &cc);
    t2 = addc32((uint32_t)(E1 >> 32), (uint32_t)O1, cc, &cc);
    t3 = addc32((uint32_t)E2, (uint32_t)(O1 >> 32), cc, &cc);
    t4 = addc32((uint32_t)(E2 >> 32), (uint32_t)O2, cc, &cc);
    t5 = addc32((uint32_t)E3, (uint32_t)(O2 >> 32), cc, &cc);
    t6 = addc32((uint32_t)(E3 >> 32), (uint32_t)O3, cc, &cc);
    t7 = t8 + (uint32_t)(O3 >> 32) + cc;  // T1 < 5p < 2^255: fits 32b
  }

  // REDC step 2 (8 limbs): T2 < 2p
  {
    uint32_t m = 0u - t0;
    uint32_t g = (t0 != 0u) ? 1u : 0u;
    uint64_t O0 = (uint64_t)m * PL[1] + t1;
    uint64_t E1 = (uint64_t)m * PL[2] + t2;
    uint64_t O1 = (uint64_t)m * PL[3] + t3;
    uint64_t E2 = (uint64_t)m * PL[4] + t4;
    uint64_t O2 = (uint64_t)m * PL[5] + t5;
    uint64_t E3 = (uint64_t)m * PL[6] + t6;
    uint64_t O3 = (uint64_t)m * PL[7] + t7;
    t0 = addc32((uint32_t)O0, g, 0u, &cc);
    t1 = addc32((uint32_t)E1, (uint32_t)(O0 >> 32), cc, &cc);
    t2 = addc32((uint32_t)(E1 >> 32), (uint32_t)O1, cc, &cc);
    t3 = addc32((uint32_t)E2, (uint32_t)(O1 >> 32), cc, &cc);
    t4 = addc32((uint32_t)(E2 >> 32), (uint32_t)O2, cc, &cc);
    t5 = addc32((uint32_t)E3, (uint32_t)(O2 >> 32), cc, &cc);
    t6 = addc32((uint32_t)(E3 >> 32), (uint32_t)O3, cc, &cc);
    t7 = (uint32_t)(O3 >> 32) + cc;       // T2 < 2p < 2^254: fits 32b
  }

  // cond_sub: subtract p iff no final borrow -> canonical; emit even limbs.
  uint32_t d0, d2, d4, d6;
  uint64_t y;
  y = (uint64_t)t0 - PL[0];                          d0 = (uint32_t)y;
  y = (uint64_t)t1 - PL[1] - ((y >> 32) & 1ull);
  y = (uint64_t)t2 - PL[2] - ((y >> 32) & 1ull);     d2 = (uint32_t)y;
  y = (uint64_t)t3 - PL[3] - ((y >> 32) & 1ull);
  y = (uint64_t)t4 - PL[4] - ((y >> 32) & 1ull);     d4 = (uint32_t)y;
  y = (uint64_t)t5 - PL[5] - ((y >> 32) & 1ull);
  y = (uint64_t)t6 - PL[6] - ((y >> 32) & 1ull);     d6 = (uint32_t)y;
  y = (uint64_t)t7 - PL[7] - ((y >> 32) & 1ull);
  bool use = (((y >> 32) & 1ull) == 0);              // no borrow -> t >= p
  v4i o;
  o.x = (int)(use ? d0 : t0);
  o.y = (int)(use ? d2 : t2);
  o.z = (int)(use ? d4 : t4);
  o.w = (int)(use ? d6 : t6);
  return o;
}

// Dual-element kernel with hand-built memory pipeline (counted vmcnt).
__global__ __launch_bounds__(256) void fr_tomont_add_dual(
    const v4i* __restrict__ in1,
    const v4i* __restrict__ in2,
    v4i* __restrict__ out,
    int half) {
  int idx = blockIdx.x * blockDim.x + threadIdx.x;
  if (idx >= half) return;
  int idxB = idx + half;

  const v4i* pA1 = in1 + idx;
  const v4i* pA2 = in2 + idx;
  const v4i* pB1 = in1 + idxB;
  const v4i* pB2 = in2 + idxB;

  v4i aA, bA, aB, bB;
  // Volatile asm loads: issue order fixed, cannot be sunk by the scheduler.
  // VMEM queue after these four: [aA, bA, aB, bB] (oldest first).
  asm volatile("global_load_dwordx4 %0, %1, off" : "=v"(aA) : "v"(pA1));
  asm volatile("global_load_dwordx4 %0, %1, off" : "=v"(bA) : "v"(pA2));
  asm volatile("global_load_dwordx4 %0, %1, off" : "=v"(aB) : "v"(pB1));
  asm volatile("global_load_dwordx4 %0, %1, off" : "=v"(bB) : "v"(pB2));

  // Wait until <=2 outstanding: retires aA,bA; aB,bB may stay in flight.
  // "+v" redefinition makes every consumer of aA/bA depend on this wait.
  asm volatile("s_waitcnt vmcnt(2)" : "+v"(aA), "+v"(bA));
  __builtin_amdgcn_sched_barrier(0);  // rule #18: block hoisting past the wait

  v4i oA = compute_one(aA, bA);       // ~600 cyc; covers aB/bB flight time
  v4i* qA = out + idx;
  asm volatile("global_store_dwordx4 %0, %1, off" :: "v"(qA), "v"(oA) : "memory");

  // Queue now [aB, bB, stA]; <=1 outstanding retires aB,bB without waiting
  // for the store to drain.
  asm volatile("s_waitcnt vmcnt(1)" : "+v"(aB), "+v"(bB));
  __builtin_amdgcn_sched_barrier(0);

  v4i oB = compute_one(aB, bB);
  v4i* qB = out + idxB;
  asm volatile("global_store_dwordx4 %0, %1, off" :: "v"(qB), "v"(oB) : "memory");
}

// Fallback: one element per thread (R11 structure) for odd n.
__global__ __launch_bounds__(256) void fr_tomont_add_single(
    const v4i* __restrict__ in1,
    const v4i* __restrict__ in2,
    v4i* __restrict__ out,
    int n) {
  int idx = blockIdx.x * blockDim.x + threadIdx.x;
  if (idx >= n) return;
  v4i o = compute_one(in1[idx], in2[idx]);
  __builtin_nontemporal_store(o, out + idx);
}

extern "C" void kernel_launch(void* const* d_in, const int* in_sizes, int n_in,
                              void* d_out, int out_size, void* d_ws, size_t ws_size,
                              hipStream_t stream) {
  const v4i* in1 = (const v4i*)d_in[0];
  const v4i* in2 = (const v4i*)d_in[1];
  v4i* out = (v4i*)d_out;
  int n = in_sizes[0] / 4;  // (N,4) -> N elements

  const int block = 256;
  if ((n & 1) == 0) {
    int half = n / 2;
    int grid = (half + block - 1) / block;
    fr_tomont_add_dual<<<grid, block, 0, stream>>>(in1, in2, out, half);
  } else {
    int grid = (n + block - 1) / block;
    fr_tomont_add_single<<<grid, block, 0, stream>>>(in1, in2, out, n);
  }
}

// Round 13
// 35.259 us; speedup vs baseline: 1.0047x; 1.0047x over previous
//
#include <hip/hip_runtime.h>
#include <stdint.h>

// BLS12-377 Fr: p = 0x12ab655e9a2ca55660b44d1e5c37b00159aa76fed00000010a11800000000001
//
// Reference computes (a*R mod p + b*R mod p) mod p, canonical in [0,p), R = 2^256.
// Inputs a,b each have 4 64-bit limbs < 2^31 (values < 2^223), so a+b < 2^224 < p and
// the result equals (a+b)*R mod p. With s_k = a_k + b_k (< 2^32, no inter-limb carry),
// result = (sum_k s_k * D_k) * 2^-64 mod p where D_k = 2^(320+64k) mod p.
//
// Bounds: T0 = sum s_k*D_k < 2^34*p (9 limbs, limb8 < 2^31).
//   REDC step 1: T1 < 5p < 2^255  (8 limbs, top < 2^31)
//   REDC step 2: T2 < 2p          (single cond_sub -> canonical, bit-exact vs ref)
//
// Harness dtypes: inputs int32[N*4] (limbs < 2^31), output int32[N*4] = low 32 bits
// of each 64-bit output word = even 32-bit limbs of the canonical residue.
//
// FINAL (= Round 8, best measured: 34.3 us). Session findings:
//  - Algebraic collapse to ONE short Montgomery pipeline (4 mul rows vs 2 full
//    montmuls + add): 40.4 -> 35.4 us.
//  - 32-bit-only persistent state (64-bit temps only inside mads): -1.1 us,
//    VGPR 32 -> 16.
//  - Duration is INVARIANT (34.3-35.4) across 25% VALU-work reduction (R11
//    even/odd split) and every scheduling structure tried (inline-call x2,
//    statement interleave, prefetch pipeline, sched_barrier, asm pins,
//    hand-built counted-vmcnt asm pipeline): memory-system-bound.
//  - Compulsory traffic 201 MB (134R + 67W, zero reuse, zero over-fetch per
//    FETCH/WRITE counters) at 34.3 us = 5.87 TB/s = 93% of the 6.29 TB/s
//    measured streaming ceiling, with ~58% concurrent VALU issue. Roofline.

#define MASK32 0xffffffffull

namespace {

constexpr uint32_t PL[8] = {
  0x00000001u, 0x0a118000u, 0xd0000001u, 0x59aa76feu,
  0x5c37b001u, 0x60b44d1eu, 0x9a2ca556u, 0x12ab655eu
};

struct U256 { uint32_t l[8]; };

constexpr bool geq_p(const U256& x) {
  for (int i = 7; i >= 0; --i) {
    if (x.l[i] != PL[i]) return x.l[i] > PL[i];
  }
  return true;  // equal
}

// 2^e mod p via double-and-reduce from 2^252 (< p since p > 2^252).
constexpr U256 pow2_mod(int e) {
  U256 x{};
  for (int i = 0; i < 8; ++i) x.l[i] = 0;
  x.l[7] = 0x10000000u;  // 2^252
  for (int it = 0; it < e - 252; ++it) {
    uint32_t carry = 0;
    for (int j = 0; j < 8; ++j) {
      uint32_t nc = x.l[j] >> 31;
      x.l[j] = (x.l[j] << 1) | carry;
      carry = nc;
    }
    if (geq_p(x)) {
      uint64_t borrow = 0;
      for (int j = 0; j < 8; ++j) {
        uint64_t d = (uint64_t)x.l[j] - (uint64_t)PL[j] - borrow;
        x.l[j] = (uint32_t)d;
        borrow = (d >> 32) & 1ull;
      }
    }
  }
  return x;
}

constexpr U256 D0 = pow2_mod(320);
constexpr U256 D1 = pow2_mod(384);
constexpr U256 D2 = pow2_mod(448);
constexpr U256 D3 = pow2_mod(512);

}  // namespace

typedef int v4i __attribute__((ext_vector_type(4)));

__global__ __launch_bounds__(256) void fr_tomont_add_kernel(
    const v4i* __restrict__ in1,
    const v4i* __restrict__ in2,
    v4i* __restrict__ out,
    int n) {
  int idx = blockIdx.x * blockDim.x + threadIdx.x;
  if (idx >= n) return;

  v4i av = in1[idx];
  v4i bv = in2[idx];

  // s_k = a_k + b_k; input limbs < 2^31 so the 32-bit sum cannot overflow.
  uint32_t s0 = (uint32_t)av.x + (uint32_t)bv.x;
  uint32_t s1 = (uint32_t)av.y + (uint32_t)bv.y;
  uint32_t s2 = (uint32_t)av.z + (uint32_t)bv.z;
  uint32_t s3 = (uint32_t)av.w + (uint32_t)bv.w;

  // All persistent state is 32-bit; x is the only 64-bit temp.
  uint32_t t0, t1, t2, t3, t4, t5, t6, t7, t8;
  uint64_t x;
  uint32_t c;

  // ---- Row 0: t = s0 * D0 ----
  x = (uint64_t)s0 * D0.l[0];            t0 = (uint32_t)x; c = (uint32_t)(x >> 32);
  x = (uint64_t)s0 * D0.l[1] + c;        t1 = (uint32_t)x; c = (uint32_t)(x >> 32);
  x = (uint64_t)s0 * D0.l[2] + c;        t2 = (uint32_t)x; c = (uint32_t)(x >> 32);
  x = (uint64_t)s0 * D0.l[3] + c;        t3 = (uint32_t)x; c = (uint32_t)(x >> 32);
  x = (uint64_t)s0 * D0.l[4] + c;        t4 = (uint32_t)x; c = (uint32_t)(x >> 32);
  x = (uint64_t)s0 * D0.l[5] + c;        t5 = (uint32_t)x; c = (uint32_t)(x >> 32);
  x = (uint64_t)s0 * D0.l[6] + c;        t6 = (uint32_t)x; c = (uint32_t)(x >> 32);
  x = (uint64_t)s0 * D0.l[7] + c;        t7 = (uint32_t)x; t8 = (uint32_t)(x >> 32);

  // ---- Row 1: t += s1 * D1 ----
  x = (uint64_t)s1 * D1.l[0] + t0;       t0 = (uint32_t)x; c = (uint32_t)(x >> 32);
  x = (uint64_t)s1 * D1.l[1] + t1 + c;   t1 = (uint32_t)x; c = (uint32_t)(x >> 32);
  x = (uint64_t)s1 * D1.l[2] + t2 + c;   t2 = (uint32_t)x; c = (uint32_t)(x >> 32);
  x = (uint64_t)s1 * D1.l[3] + t3 + c;   t3 = (uint32_t)x; c = (uint32_t)(x >> 32);
  x = (uint64_t)s1 * D1.l[4] + t4 + c;   t4 = (uint32_t)x; c = (uint32_t)(x >> 32);
  x = (uint64_t)s1 * D1.l[5] + t5 + c;   t5 = (uint32_t)x; c = (uint32_t)(x >> 32);
  x = (uint64_t)s1 * D1.l[6] + t6 + c;   t6 = (uint32_t)x; c = (uint32_t)(x >> 32);
  x = (uint64_t)s1 * D1.l[7] + t7 + c;   t7 = (uint32_t)x; t8 += (uint32_t)(x >> 32);

  // ---- Row 2: t += s2 * D2 ----
  x = (uint64_t)s2 * D2.l[0] + t0;       t0 = (uint32_t)x; c = (uint32_t)(x >> 32);
  x = (uint64_t)s2 * D2.l[1] + t1 + c;   t1 = (uint32_t)x; c = (uint32_t)(x >> 32);
  x = (uint64_t)s2 * D2.l[2] + t2 + c;   t2 = (uint32_t)x; c = (uint32_t)(x >> 32);
  x = (uint64_t)s2 * D2.l[3] + t3 + c;   t3 = (uint32_t)x; c = (uint32_t)(x >> 32);
  x = (uint64_t)s2 * D2.l[4] + t4 + c;   t4 = (uint32_t)x; c = (uint32_t)(x >> 32);
  x = (uint64_t)s2 * D2.l[5] + t5 + c;   t5 = (uint32_t)x; c = (uint32_t)(x >> 32);
  x = (uint64_t)s2 * D2.l[6] + t6 + c;   t6 = (uint32_t)x; c = (uint32_t)(x >> 32);
  x = (uint64_t)s2 * D2.l[7] + t7 + c;   t7 = (uint32_t)x; t8 += (uint32_t)(x >> 32);

  // ---- Row 3: t += s3 * D3 ----
  x = (uint64_t)s3 * D3.l[0] + t0;       t0 = (uint32_t)x; c = (uint32_t)(x >> 32);
  x = (uint64_t)s3 * D3.l[1] + t1 + c;   t1 = (uint32_t)x; c = (uint32_t)(x >> 32);
  x = (uint64_t)s3 * D3.l[2] + t2 + c;   t2 = (uint32_t)x; c = (uint32_t)(x >> 32);
  x = (uint64_t)s3 * D3.l[3] + t3 + c;   t3 = (uint32_t)x; c = (uint32_t)(x >> 32);
  x = (uint64_t)s3 * D3.l[4] + t4 + c;   t4 = (uint32_t)x; c = (uint32_t)(x >> 32);
  x = (uint64_t)s3 * D3.l[5] + t5 + c;   t5 = (uint32_t)x; c = (uint32_t)(x >> 32);
  x = (uint64_t)s3 * D3.l[6] + t6 + c;   t6 = (uint32_t)x; c = (uint32_t)(x >> 32);
  x = (uint64_t)s3 * D3.l[7] + t7 + c;   t7 = (uint32_t)x; t8 += (uint32_t)(x >> 32);

  // ---- REDC step 1 (9 -> 8 limbs): m = -t0 mod 2^32 (p[0] == 1) ----
  {
    uint32_t m = 0u - t0;
    c = (t0 != 0u) ? 1u : 0u;            // carry of t0 + m*1
    x = (uint64_t)m * PL[1] + t1 + c;    t0 = (uint32_t)x; c = (uint32_t)(x >> 32);
    x = (uint64_t)m * PL[2] + t2 + c;    t1 = (uint32_t)x; c = (uint32_t)(x >> 32);
    x = (uint64_t)m * PL[3] + t3 + c;    t2 = (uint32_t)x; c = (uint32_t)(x >> 32);
    x = (uint64_t)m * PL[4] + t4 + c;    t3 = (uint32_t)x; c = (uint32_t)(x >> 32);
    x = (uint64_t)m * PL[5] + t5 + c;    t4 = (uint32_t)x; c = (uint32_t)(x >> 32);
    x = (uint64_t)m * PL[6] + t6 + c;    t5 = (uint32_t)x; c = (uint32_t)(x >> 32);
    x = (uint64_t)m * PL[7] + t7 + c;    t6 = (uint32_t)x; c = (uint32_t)(x >> 32);
    t7 = t8 + c;                          // T1 < 5p < 2^255: no overflow
  }

  // ---- REDC step 2 (8 limbs): T2 < 2p ----
  {
    uint32_t m = 0u - t0;
    c = (t0 != 0u) ? 1u : 0u;
    x = (uint64_t)m * PL[1] + t1 + c;    t0 = (uint32_t)x; c = (uint32_t)(x >> 32);
    x = (uint64_t)m * PL[2] + t2 + c;    t1 = (uint32_t)x; c = (uint32_t)(x >> 32);
    x = (uint64_t)m * PL[3] + t3 + c;    t2 = (uint32_t)x; c = (uint32_t)(x >> 32);
    x = (uint64_t)m * PL[4] + t4 + c;    t3 = (uint32_t)x; c = (uint32_t)(x >> 32);
    x = (uint64_t)m * PL[5] + t5 + c;    t4 = (uint32_t)x; c = (uint32_t)(x >> 32);
    x = (uint64_t)m * PL[6] + t6 + c;    t5 = (uint32_t)x; c = (uint32_t)(x >> 32);
    x = (uint64_t)m * PL[7] + t7 + c;    t6 = (uint32_t)x; t7 = (uint32_t)(x >> 32);
  }

  // ---- cond_sub: T2 < 2p; subtract p iff no borrow -> canonical residue ----
  uint32_t d0, d2, d4, d6;
  {
    uint64_t y;
    y = (uint64_t)t0 - PL[0];                          d0 = (uint32_t)y;
    y = (uint64_t)t1 - PL[1] - ((y >> 32) & 1ull);     /* d1 */
    y = (uint64_t)t2 - PL[2] - ((y >> 32) & 1ull);     d2 = (uint32_t)y;
    y = (uint64_t)t3 - PL[3] - ((y >> 32) & 1ull);     /* d3 */
    y = (uint64_t)t4 - PL[4] - ((y >> 32) & 1ull);     d4 = (uint32_t)y;
    y = (uint64_t)t5 - PL[5] - ((y >> 32) & 1ull);     /* d5 */
    y = (uint64_t)t6 - PL[6] - ((y >> 32) & 1ull);     d6 = (uint32_t)y;
    y = (uint64_t)t7 - PL[7] - ((y >> 32) & 1ull);
    bool use = (((y >> 32) & 1ull) == 0);              // no final borrow -> t >= p
    v4i o;
    o.x = (int)(use ? d0 : t0);
    o.y = (int)(use ? d2 : t2);
    o.z = (int)(use ? d4 : t4);
    o.w = (int)(use ? d6 : t6);
    // Non-temporal store: output never re-read.
    __builtin_nontemporal_store(o, out + idx);
  }
}

extern "C" void kernel_launch(void* const* d_in, const int* in_sizes, int n_in,
                              void* d_out, int out_size, void* d_ws, size_t ws_size,
                              hipStream_t stream) {
  const v4i* in1 = (const v4i*)d_in[0];
  const v4i* in2 = (const v4i*)d_in[1];
  v4i* out = (v4i*)d_out;
  int n = in_sizes[0] / 4;  // (N,4) -> N elements

  const int block = 256;
  const int grid = (n + block - 1) / block;
  fr_tomont_add_kernel<<<grid, block, 0, stream>>>(in1, in2, out, n);
}